// Round 2
// baseline (333.823 us; speedup 1.0000x reference)
//
#include <hip/hip_runtime.h>

#define B_   32
#define D_   256
#define HW_  1024
#define N_   32768
#define K_   1024
#define DHW  (D_ * HW_)      // 262144
#define MARGIN 0.05f

typedef __attribute__((ext_vector_type(8)))  short bf16x8;
typedef __attribute__((ext_vector_type(16))) float f32x16;

union Frag { uint u[4]; uint4 q; bf16x8 v; };

// ---- float -> (bf16 hi, bf16 lo) split, RNE ----
__device__ inline void bf16_split(float x, uint& hb, uint& lb) {
    uint ub = __float_as_uint(x);
    hb = (ub + 0x7fffu + ((ub >> 16) & 1u)) >> 16;          // bf16 bits of hi (RNE)
    float hf = __uint_as_float(hb << 16);
    float r  = x - hf;
    uint ur = __float_as_uint(r);
    lb = (ur + 0x7fffu + ((ur >> 16) & 1u)) >> 16;          // bf16 bits of lo
}

// ================= prep_x: x -> paired hi/lo bf16 planes in d_out scratch ==========
// xh layout: [128 dp][32768 n] u32 = (h(2dp) | h(2dp+1)<<16), xl same for lo.
__global__ __launch_bounds__(256)
void prep_x(const float* __restrict__ x, uint* __restrict__ xh, uint* __restrict__ xl) {
    int b  = blockIdx.x >> 7;
    int dp = blockIdx.x & 127;
    int hw0 = threadIdx.x * 4;
    const float4 r0 = *reinterpret_cast<const float4*>(&x[(size_t)b * DHW + (size_t)(2*dp)   * HW_ + hw0]);
    const float4 r1 = *reinterpret_cast<const float4*>(&x[(size_t)b * DHW + (size_t)(2*dp+1) * HW_ + hw0]);
    float a0[4] = { r0.x, r0.y, r0.z, r0.w };
    float a1[4] = { r1.x, r1.y, r1.z, r1.w };
    uint wh[4], wl[4];
    #pragma unroll
    for (int e = 0; e < 4; ++e) {
        uint h0, l0, h1, l1;
        bf16_split(a0[e], h0, l0);
        bf16_split(a1[e], h1, l1);
        wh[e] = h0 | (h1 << 16);
        wl[e] = l0 | (l1 << 16);
    }
    size_t o = (size_t)dp * N_ + b * HW_ + hw0;
    *reinterpret_cast<uint4*>(&xh[o]) = make_uint4(wh[0], wh[1], wh[2], wh[3]);
    *reinterpret_cast<uint4*>(&xl[o]) = make_uint4(wl[0], wl[1], wl[2], wl[3]);
}

// ================= prep_cb: codebook -> tiled hi/lo planes + csq ==========
// cbt layout (u32): [p 2][chunk 8][gg 4][col 1024][jj 4]
__global__ __launch_bounds__(256)
void prep_cb(const float* __restrict__ cb, uint* __restrict__ cbt, float* __restrict__ csq) {
    __shared__ uint sh[256], sl[256];
    __shared__ float rr[4];
    int k = blockIdx.x, d = threadIdx.x;
    float v = cb[(size_t)k * D_ + d];
    uint hb, lb; bf16_split(v, hb, lb);
    sh[d] = hb; sl[d] = lb;
    float s = v * v;
    #pragma unroll
    for (int off = 32; off >= 1; off >>= 1) s += __shfl_xor(s, off, 64);
    if ((d & 63) == 0) rr[d >> 6] = s;
    __syncthreads();
    if (d == 0) csq[k] = (rr[0] + rr[1]) + (rr[2] + rr[3]);
    int p  = d >> 7;          // 0: hi plane, 1: lo plane
    int dp = d & 127;
    int chunk = dp >> 4, dpl = dp & 15;
    int gg = dpl >> 2, jj = dpl & 3;
    const uint* src = p ? sl : sh;
    uint w = src[2*dp] | (src[2*dp + 1] << 16);
    cbt[(size_t)((((p*8 + chunk)*4 + gg) << 10) + k) * 4 + jj] = w;
}

// ================= main MFMA distance + partial top-2 argmin ==========
// grid: 1024 blocks = 256 token-tiles (x128) * 4 code-tiles (x256), codetile-major.
__global__ __launch_bounds__(512)
void vq_gemm(const uint* __restrict__ xh, const uint* __restrict__ xl,
             const uint* __restrict__ cbt, const float* __restrict__ csq,
             float* __restrict__ pv1, int* __restrict__ pk1, float* __restrict__ pv2) {
    __shared__ __align__(16) uint Bs[2][4][256][4];   // [plane][gg][col][jj] = 32 KB

    const int tid  = threadIdx.x;
    const int lane = tid & 63;
    const int w    = tid >> 6;
    const int sub  = lane >> 5, l31 = lane & 31;
    const int wm   = w >> 2,    wn  = w & 3;
    const int tokt  = (blockIdx.x & 255) * 128;
    const int cbt_i = blockIdx.x >> 8;
    const int code0 = cbt_i * 256;
    const int na = tokt + wm * 64 + l31;

    f32x16 acc00 = {}, acc01 = {}, acc10 = {}, acc11 = {};

    uint4 ld[4];
    // preload chunk 0 staging regs
    #pragma unroll
    for (int it = 0; it < 4; ++it) {
        int seg = it*2 + (tid >> 8); int p = seg >> 2, gg = seg & 3;
        ld[it] = *reinterpret_cast<const uint4*>(
            &cbt[(size_t)((((p*8 + 0)*4 + gg) << 10) + code0 + (tid & 255)) * 4]);
    }

    for (int chunk = 0; chunk < 8; ++chunk) {
        // write staged regs -> LDS
        #pragma unroll
        for (int it = 0; it < 4; ++it) {
            int seg = it*2 + (tid >> 8); int p = seg >> 2, gg = seg & 3;
            *reinterpret_cast<uint4*>(&Bs[p][gg][tid & 255][0]) = ld[it];
        }
        __syncthreads();
        if (chunk < 7) {
            #pragma unroll
            for (int it = 0; it < 4; ++it) {
                int seg = it*2 + (tid >> 8); int p = seg >> 2, gg = seg & 3;
                ld[it] = *reinterpret_cast<const uint4*>(
                    &cbt[(size_t)((((p*8 + chunk + 1)*4 + gg) << 10) + code0 + (tid & 255)) * 4]);
            }
        }
        // compute on this chunk (32 d = 2 k-steps of 16)
        #pragma unroll
        for (int ks = 0; ks < 2; ++ks) {
            const int dpb = chunk*16 + ks*8 + sub*4;
            Frag ah0, ah1, al0, al1;
            #pragma unroll
            for (int jj = 0; jj < 4; ++jj) {
                int off = (dpb + jj) * N_ + na;
                ah0.u[jj] = xh[off];       ah1.u[jj] = xh[off + 32];
                al0.u[jj] = xl[off];       al1.u[jj] = xl[off + 32];
            }
            const int gg = ks*2 + sub;
            Frag bh0, bh1, bl0, bl1;
            bh0.q = *reinterpret_cast<const uint4*>(&Bs[0][gg][wn*64 + l31][0]);
            bh1.q = *reinterpret_cast<const uint4*>(&Bs[0][gg][wn*64 + 32 + l31][0]);
            bl0.q = *reinterpret_cast<const uint4*>(&Bs[1][gg][wn*64 + l31][0]);
            bl1.q = *reinterpret_cast<const uint4*>(&Bs[1][gg][wn*64 + 32 + l31][0]);

            acc00 = __builtin_amdgcn_mfma_f32_32x32x16_bf16(ah0.v, bh0.v, acc00, 0, 0, 0);
            acc00 = __builtin_amdgcn_mfma_f32_32x32x16_bf16(ah0.v, bl0.v, acc00, 0, 0, 0);
            acc00 = __builtin_amdgcn_mfma_f32_32x32x16_bf16(al0.v, bh0.v, acc00, 0, 0, 0);

            acc01 = __builtin_amdgcn_mfma_f32_32x32x16_bf16(ah0.v, bh1.v, acc01, 0, 0, 0);
            acc01 = __builtin_amdgcn_mfma_f32_32x32x16_bf16(ah0.v, bl1.v, acc01, 0, 0, 0);
            acc01 = __builtin_amdgcn_mfma_f32_32x32x16_bf16(al0.v, bh1.v, acc01, 0, 0, 0);

            acc10 = __builtin_amdgcn_mfma_f32_32x32x16_bf16(ah1.v, bh0.v, acc10, 0, 0, 0);
            acc10 = __builtin_amdgcn_mfma_f32_32x32x16_bf16(ah1.v, bl0.v, acc10, 0, 0, 0);
            acc10 = __builtin_amdgcn_mfma_f32_32x32x16_bf16(al1.v, bh0.v, acc10, 0, 0, 0);

            acc11 = __builtin_amdgcn_mfma_f32_32x32x16_bf16(ah1.v, bh1.v, acc11, 0, 0, 0);
            acc11 = __builtin_amdgcn_mfma_f32_32x32x16_bf16(ah1.v, bl1.v, acc11, 0, 0, 0);
            acc11 = __builtin_amdgcn_mfma_f32_32x32x16_bf16(al1.v, bh1.v, acc11, 0, 0, 0);
        }
        __syncthreads();
    }

    // ---- epilogue: s = csq - 2*dot; per-token top-2 over this block's 256 codes ----
    const int c0 = code0 + wn*64 + l31;
    const int c1 = c0 + 32;
    const float cs0 = csq[c0];
    const float cs1 = csq[c1];

    // per-block merge scratch (reuse Bs memory)
    float* redv1 = reinterpret_cast<float*>(&Bs[0][0][0][0]);   // [128][4]
    float* redv2 = redv1 + 512;                                 // [128][4]
    int*   redk  = reinterpret_cast<int*>(redv2 + 512);         // [128][4]

    #pragma unroll
    for (int mf = 0; mf < 2; ++mf) {
        const f32x16& a0 = mf ? acc10 : acc00;
        const f32x16& a1 = mf ? acc11 : acc01;
        #pragma unroll
        for (int r = 0; r < 16; ++r) {
            float s0 = fmaf(-2.f, a0[r], cs0);
            float s1 = fmaf(-2.f, a1[r], cs1);
            float v1, v2; int k1;
            if (s1 < s0) { v1 = s1; k1 = c1; v2 = s0; }
            else         { v1 = s0; k1 = c0; v2 = s1; }
            #pragma unroll
            for (int m = 1; m < 32; m <<= 1) {
                float ov1 = __shfl_xor(v1, m, 64);
                int   ok1 = __shfl_xor(k1, m, 64);
                float ov2 = __shfl_xor(v2, m, 64);
                if (ov1 < v1 || (ov1 == v1 && ok1 < k1)) {
                    v2 = fminf(v1, ov2); v1 = ov1; k1 = ok1;
                } else {
                    v2 = fminf(v2, ov1);
                }
            }
            if (l31 == 0) {
                int crow = (r & 3) + 8*(r >> 2) + 4*sub;
                int tl = wm*64 + mf*32 + crow;
                redv1[tl*4 + wn] = v1;
                redv2[tl*4 + wn] = v2;
                redk [tl*4 + wn] = k1;
            }
        }
    }
    __syncthreads();
    if (tid < 128) {
        float v1 = redv1[tid*4], v2 = redv2[tid*4]; int k1 = redk[tid*4];
        #pragma unroll
        for (int q = 1; q < 4; ++q) {
            float a1 = redv1[tid*4 + q], a3 = redv2[tid*4 + q];
            int   a2 = redk [tid*4 + q];
            if (a1 < v1 || (a1 == v1 && a2 < k1)) { v2 = fminf(v1, a3); v1 = a1; k1 = a2; }
            else                                  { v2 = fminf(v2, a1); }
        }
        int n = tokt + tid;
        pv1[cbt_i * N_ + n] = v1;
        pk1[cbt_i * N_ + n] = k1;
        pv2[cbt_i * N_ + n] = v2;
    }
}

// ================= combine partials, flag near-ties ==========
__global__ __launch_bounds__(256)
void vq_combine(const float* __restrict__ pv1, const int* __restrict__ pk1,
                const float* __restrict__ pv2, int* __restrict__ bestk,
                int* __restrict__ rcount, int* __restrict__ rlist) {
    int n = blockIdx.x * 256 + threadIdx.x;
    float v1 = pv1[n]; int k1 = pk1[n]; float v2 = pv2[n];
    #pragma unroll
    for (int c = 1; c < 4; ++c) {
        float a1 = pv1[c * N_ + n], a3 = pv2[c * N_ + n];
        int   a2 = pk1[c * N_ + n];
        if (a1 < v1 || (a1 == v1 && a2 < k1)) { v2 = fminf(v1, a3); v1 = a1; k1 = a2; }
        else                                  { v2 = fminf(v2, a1); }
    }
    bestk[n] = k1;
    if (v2 - v1 < MARGIN) {
        int p = atomicAdd(rcount, 1);
        rlist[p] = n;
    }
}

// ================= exact fp32 refine for flagged tokens ==========
__global__ __launch_bounds__(256)
void vq_refine(const float* __restrict__ x, const float* __restrict__ cb,
               const float* __restrict__ csq, const int* __restrict__ rcount,
               const int* __restrict__ rlist, int* __restrict__ bestk) {
    __shared__ float lx[256];
    __shared__ float rr[4];
    __shared__ float rv[4];
    __shared__ int   rk[4];
    const int tid = threadIdx.x;
    const int cnt = rcount[0];
    for (int i = blockIdx.x; i < cnt; i += gridDim.x) {
        int n = rlist[i];
        int b = n >> 10, hw = n & 1023;
        float xv = x[(size_t)b * DHW + (size_t)tid * HW_ + hw];
        lx[tid] = xv;
        float s = xv * xv;
        #pragma unroll
        for (int off = 32; off >= 1; off >>= 1) s += __shfl_xor(s, off, 64);
        if ((tid & 63) == 0) rr[tid >> 6] = s;
        __syncthreads();
        float xsq = (rr[0] + rr[1]) + (rr[2] + rr[3]);
        const float* c0p = cb + (size_t)tid * D_;
        float d0 = 0.f, d1 = 0.f, d2 = 0.f, d3 = 0.f;
        for (int d = 0; d < 256; ++d) {
            float lv = lx[d];
            d0 = fmaf(lv, c0p[d],            d0);
            d1 = fmaf(lv, c0p[256*256 + d],  d1);
            d2 = fmaf(lv, c0p[512*256 + d],  d2);
            d3 = fmaf(lv, c0p[768*256 + d],  d3);
        }
        float bv = 3.4e38f; int bk = 0;
        float dd[4] = { d0, d1, d2, d3 };
        #pragma unroll
        for (int c = 0; c < 4; ++c) {
            int code = tid + c * 256;
            float dist = fmaf(-2.f, dd[c], xsq) + csq[code];
            if (dist < bv || (dist == bv && code < bk)) { bv = dist; bk = code; }
        }
        #pragma unroll
        for (int m = 1; m < 64; m <<= 1) {
            float ov = __shfl_xor(bv, m, 64);
            int   ok = __shfl_xor(bk, m, 64);
            if (ov < bv || (ov == bv && ok < bk)) { bv = ov; bk = ok; }
        }
        if ((tid & 63) == 0) { rv[tid >> 6] = bv; rk[tid >> 6] = bk; }
        __syncthreads();
        if (tid == 0) {
            float fv = rv[0]; int fk = rk[0];
            #pragma unroll
            for (int q = 1; q < 4; ++q) {
                if (rv[q] < fv || (rv[q] == fv && rk[q] < fk)) { fv = rv[q]; fk = rk[q]; }
            }
            bestk[n] = fk;
        }
        __syncthreads();
    }
}

// ================= gather codewords, write out/idx, losses ==========
__global__ __launch_bounds__(256)
void vq_gather(const float* __restrict__ x, const float* __restrict__ cb,
               const int* __restrict__ bestk, float* __restrict__ out,
               float* __restrict__ oidx, float* __restrict__ oloss) {
    int n0 = blockIdx.x * 64;
    int tid = threadIdx.x;
    int j = tid & 63, dg = tid >> 6;
    int n = n0 + j;
    int b = n >> 10, hw = n & 1023;
    int k = bestk[n];
    const float* cw = cb + (size_t)k * D_;
    size_t basex = (size_t)b * DHW + hw;
    float lsum = 0.f;
    #pragma unroll 4
    for (int d = dg * 64; d < dg * 64 + 64; ++d) {
        float q  = cw[d];
        float xv = x[basex + (size_t)d * HW_];
        out[basex + (size_t)d * HW_] = q;
        float df = xv - q;
        lsum = fmaf(df, df, lsum);
    }
    #pragma unroll
    for (int off = 32; off >= 1; off >>= 1) lsum += __shfl_xor(lsum, off, 64);
    if ((tid & 63) == 0) {
        float v = lsum * (1.0f / 8388608.0f);
        atomicAdd(&oloss[0], v);
        atomicAdd(&oloss[1], v);
    }
    if (tid < 64) oidx[n0 + tid] = (float)bestk[n0 + tid];
}

extern "C" void kernel_launch(void* const* d_in, const int* in_sizes, int n_in,
                              void* d_out, int out_size, void* d_ws, size_t ws_size,
                              hipStream_t stream) {
    const float* x  = (const float*)d_in[0];
    const float* cb = (const float*)d_in[1];

    float* out   = (float*)d_out;            // [B,D,H,W] = 8388608 floats
    float* oidx  = out + 8388608;            // [B,H,W]   = 32768 floats
    float* oloss = out + 8388608 + 32768;    // 2 floats

    // d_out reused as scratch for the bf16 hi/lo planes of x (exactly 32 MB),
    // overwritten by vq_gather at the end.
    uint* xh = (uint*)d_out;                 // [128][32768]
    uint* xl = xh + 128 * 32768;             // [128][32768]

    // workspace layout (u32/f32 units)
    uint*  cbt    = (uint*)d_ws;             // 262144 u32 (1 MB)
    float* csq    = (float*)d_ws + 262144;   // 1024
    float* pv1    = (float*)d_ws + 263168;   // 4*32768
    int*   pk1    = (int*)  d_ws + 394240;   // 4*32768
    float* pv2    = (float*)d_ws + 525312;   // 4*32768
    int*   bestk  = (int*)  d_ws + 656384;   // 32768
    int*   rcount = (int*)  d_ws + 689152;   // 1
    int*   rlist  = (int*)  d_ws + 689156;   // 32768

    hipMemsetAsync(oloss, 0, 2 * sizeof(float), stream);
    hipMemsetAsync(rcount, 0, sizeof(int), stream);

    prep_x  <<<4096, 256, 0, stream>>>(x, xh, xl);
    prep_cb <<<1024, 256, 0, stream>>>(cb, cbt, csq);
    vq_gemm <<<1024, 512, 0, stream>>>(xh, xl, cbt, csq, pv1, pk1, pv2);
    vq_combine<<<128, 256, 0, stream>>>(pv1, pk1, pv2, bestk, rcount, rlist);
    vq_refine <<<256, 256, 0, stream>>>(x, cb, csq, rcount, rlist, bestk);
    vq_gather <<<512, 256, 0, stream>>>(x, cb, bestk, out, oidx, oloss);
}

// Round 3
// 264.888 us; speedup vs baseline: 1.2602x; 1.2602x over previous
//
#include <hip/hip_runtime.h>

#define B_   32
#define D_   256
#define HW_  1024
#define N_   32768
#define K_   1024
#define DHW  (D_ * HW_)      // 262144
#define MARGIN 0.3f

typedef __attribute__((ext_vector_type(8)))  short bf16x8;
typedef __attribute__((ext_vector_type(16))) float f32x16;

union FragU { uint4 q; bf16x8 v; };

__device__ inline uint bf16rne(float x) {
    uint ub = __float_as_uint(x);
    return (ub + 0x7fffu + ((ub >> 16) & 1u)) >> 16;
}

// ================= prep_x: x -> bf16-hi plane, token-major [token][32 g] uint4 ====
// g covers d = 8g..8g+8 ; uint jj = (bf16(d even) | bf16(d odd)<<16)
__global__ __launch_bounds__(256)
void prep_x(const float* __restrict__ x, uint4* __restrict__ xg) {
    const int tok0 = blockIdx.x * 64;
    const int b = tok0 >> 10, hw0 = tok0 & 1023;
    const int tokl = threadIdx.x & 63;
    const int gq = threadIdx.x >> 6;
    #pragma unroll
    for (int it = 0; it < 8; ++it) {
        int g = it * 4 + gq;
        const float* xp = x + (size_t)b * DHW + (size_t)(g * 8) * HW_ + hw0 + tokl;
        uint w[4];
        #pragma unroll
        for (int jj = 0; jj < 4; ++jj) {
            float e0 = xp[(size_t)(2 * jj) * HW_];
            float e1 = xp[(size_t)(2 * jj + 1) * HW_];
            w[jj] = bf16rne(e0) | (bf16rne(e1) << 16);
        }
        xg[(size_t)(tok0 + tokl) * 32 + g] = make_uint4(w[0], w[1], w[2], w[3]);
    }
}

// ================= prep_cb: codebook -> hi/lo tiled planes + csq ==========
// cbt layout: [chunk 8][code 1024][8 g] uint4 ; g = p*4+gg, dpairs = chunk*16+gg*4+jj
__global__ __launch_bounds__(256)
void prep_cb(const float* __restrict__ cb, uint4* __restrict__ cbt, float* __restrict__ csq) {
    __shared__ uint sh[256], sl[256];
    __shared__ float rr[4];
    const int k = blockIdx.x, d = threadIdx.x;
    float v = cb[(size_t)k * D_ + d];
    uint hb = bf16rne(v);
    float hf = __uint_as_float(hb << 16);
    uint lb = bf16rne(v - hf);
    sh[d] = hb; sl[d] = lb;
    float s = v * v;
    #pragma unroll
    for (int off = 32; off >= 1; off >>= 1) s += __shfl_xor(s, off, 64);
    if ((d & 63) == 0) rr[d >> 6] = s;
    __syncthreads();
    if (d == 0) csq[k] = (rr[0] + rr[1]) + (rr[2] + rr[3]);
    if (d < 64) {
        int ch = d >> 3, g = d & 7;
        int p = g >> 2, gg = g & 3;
        const uint* src = p ? sl : sh;
        uint w[4];
        #pragma unroll
        for (int jj = 0; jj < 4; ++jj) {
            int dp = ch * 16 + gg * 4 + jj;
            w[jj] = src[2 * dp] | (src[2 * dp + 1] << 16);
        }
        cbt[(size_t)(ch * 1024 + k) * 8 + g] = make_uint4(w[0], w[1], w[2], w[3]);
    }
}

// ================= main: LDS-staged MFMA distances + per-lane argmin ==========
// 256 blocks x 512 thr. Block: 128 tokens x 1024 codes. codes=A(rows, hi+lo), tokens=B(cols, hi).
__global__ __launch_bounds__(512)
void vq_main(const uint4* __restrict__ xg, const uint4* __restrict__ cbt,
             const float* __restrict__ csqg, int* __restrict__ bestk,
             int* __restrict__ rcount, int* __restrict__ rlist) {
    __shared__ uint4 TkS[4096];        // 64 KB: [token 128][32 slots], slot = g ^ (t&7)
    __shared__ uint4 CbS[2][2048];     // 2x32 KB: [code 256][8 slots], slot = g ^ (c&7)
    __shared__ float csqS[1024];       // 4 KB

    const int tid = threadIdx.x;
    const int lane = tid & 63;
    const int sub = lane >> 5, l31 = lane & 31;
    const int wid = tid >> 6;
    const int wm = wid >> 1, wn = wid & 1;
    const int tok0 = blockIdx.x * 128;

    // csq -> LDS (compiler loads; drained before vmcnt bookkeeping starts)
    csqS[tid] = csqg[tid];
    csqS[tid + 512] = csqg[tid + 512];
    asm volatile("s_waitcnt vmcnt(0) lgkmcnt(0)" ::: "memory");

    // ---- stage tokens once: 8 x global_load_lds(16B) per thread ----
    {
        const int tloc = tid >> 5;           // + it*16
        const int slot = tid & 31;
        const int g = slot ^ (tloc & 7);     // (it*16) preserves t&7
        #pragma unroll
        for (int it = 0; it < 8; ++it) {
            int u = it * 512 + tid;
            const uint4* src = xg + (size_t)(tok0 + it * 16 + tloc) * 32 + g;
            __builtin_amdgcn_global_load_lds((const uint*)src, (uint*)&TkS[u], 16, 0, 0);
        }
    }
    // ---- code-chunk staging constants ----
    const int s_cl = tid >> 3;               // + it*64
    const int s_g = (tid & 7) ^ (s_cl & 7);  // (it*64) preserves c&7

    // stage chunk 0 into buf 0
    #pragma unroll
    for (int it = 0; it < 4; ++it) {
        int u = it * 512 + tid;
        int cl = it * 64 + s_cl;
        const uint4* src = cbt + (size_t)cl * 8 + s_g;
        __builtin_amdgcn_global_load_lds((const uint*)src, (uint*)&CbS[0][u], 16, 0, 0);
    }

    f32x16 acc[2][2] = {};
    float v1[2] = {3.4e38f, 3.4e38f}, v2[2] = {3.4e38f, 3.4e38f};
    int k1[2] = {0, 0};

    int cur = 0;
    for (int cc = 0; cc < 32; ++cc) {
        asm volatile("s_barrier" ::: "memory");   // B1: all reads of buf[cur^1] done
        if (cc + 1 < 32) {
            const int nct = (cc + 1) >> 3, nch = (cc + 1) & 7;
            #pragma unroll
            for (int it = 0; it < 4; ++it) {
                int u = it * 512 + tid;
                int cl = it * 64 + s_cl;
                const uint4* src = cbt + (size_t)(nch * 1024 + nct * 256 + cl) * 8 + s_g;
                __builtin_amdgcn_global_load_lds((const uint*)src, (uint*)&CbS[cur ^ 1][u], 16, 0, 0);
            }
            asm volatile("s_waitcnt vmcnt(4)" ::: "memory");  // buf[cur] arrived; keep 4 in flight
        } else {
            asm volatile("s_waitcnt vmcnt(0)" ::: "memory");
        }
        asm volatile("s_barrier" ::: "memory");   // B2: every wave's loads drained

        const int ch = cc & 7;
        #pragma unroll
        for (int ks = 0; ks < 2; ++ks) {
            FragU tf[2], cfh[2], cfl[2];
            #pragma unroll
            for (int j = 0; j < 2; ++j) {
                int t = wn * 64 + j * 32 + l31;
                int g32 = ch * 4 + ks * 2 + sub;
                tf[j].q = TkS[t * 32 + (g32 ^ (t & 7))];
            }
            #pragma unroll
            for (int f = 0; f < 2; ++f) {
                int cl = wm * 64 + f * 32 + l31;
                int gh = ks * 2 + sub;
                int gl = 4 + ks * 2 + sub;
                cfh[f].q = CbS[cur][cl * 8 + (gh ^ (cl & 7))];
                cfl[f].q = CbS[cur][cl * 8 + (gl ^ (cl & 7))];
            }
            #pragma unroll
            for (int f = 0; f < 2; ++f)
                #pragma unroll
                for (int j = 0; j < 2; ++j) {
                    acc[f][j] = __builtin_amdgcn_mfma_f32_32x32x16_bf16(cfh[f].v, tf[j].v, acc[f][j], 0, 0, 0);
                    acc[f][j] = __builtin_amdgcn_mfma_f32_32x32x16_bf16(cfl[f].v, tf[j].v, acc[f][j], 0, 0, 0);
                }
        }
        cur ^= 1;

        // ---- per-code-tile epilogue: scores + per-lane running top-2 ----
        if ((cc & 7) == 7) {
            const int ct = cc >> 3;
            const int cbase = ct * 256 + wm * 64 + sub * 4;
            #pragma unroll
            for (int f = 0; f < 2; ++f) {
                #pragma unroll
                for (int g8 = 0; g8 < 4; ++g8) {
                    float4 cs4 = *reinterpret_cast<const float4*>(&csqS[cbase + f * 32 + g8 * 8]);
                    const float csa[4] = {cs4.x, cs4.y, cs4.z, cs4.w};
                    #pragma unroll
                    for (int q = 0; q < 4; ++q) {
                        int code = cbase + f * 32 + g8 * 8 + q;
                        int r = g8 * 4 + q;
                        #pragma unroll
                        for (int j = 0; j < 2; ++j) {
                            float s = fmaf(-2.f, acc[f][j][r], csa[q]);
                            bool c = s < v1[j];
                            v2[j] = c ? v1[j] : fminf(v2[j], s);
                            k1[j] = c ? code : k1[j];
                            v1[j] = c ? s : v1[j];
                        }
                    }
                }
            }
            const f32x16 zf = {};
            #pragma unroll
            for (int f = 0; f < 2; ++f)
                #pragma unroll
                for (int j = 0; j < 2; ++j) acc[f][j] = zf;
        }
    }

    // ---- merge sub halves (codes split across sub) ----
    #pragma unroll
    for (int j = 0; j < 2; ++j) {
        float ov1 = __shfl_xor(v1[j], 32, 64);
        float ov2 = __shfl_xor(v2[j], 32, 64);
        int   ok1 = __shfl_xor(k1[j], 32, 64);
        float nv2 = fminf(fminf(v2[j], ov2), fmaxf(v1[j], ov1));
        if (ov1 < v1[j] || (ov1 == v1[j] && ok1 < k1[j])) { v1[j] = ov1; k1[j] = ok1; }
        v2[j] = nv2;
    }
    __syncthreads();
    float* red = (float*)&CbS[0][0];   // alias: [4 wm][128 token][4]
    if (sub == 0) {
        #pragma unroll
        for (int j = 0; j < 2; ++j) {
            int t = wn * 64 + j * 32 + l31;
            red[(wm * 128 + t) * 4 + 0] = v1[j];
            red[(wm * 128 + t) * 4 + 1] = v2[j];
            red[(wm * 128 + t) * 4 + 2] = __int_as_float(k1[j]);
        }
    }
    __syncthreads();
    if (tid < 128) {
        float bv1 = red[tid * 4], bv2 = red[tid * 4 + 1];
        int bk = __float_as_int(red[tid * 4 + 2]);
        #pragma unroll
        for (int m = 1; m < 4; ++m) {
            float a1 = red[(m * 128 + tid) * 4], a2 = red[(m * 128 + tid) * 4 + 1];
            int ak = __float_as_int(red[(m * 128 + tid) * 4 + 2]);
            float nv2 = fminf(fminf(bv2, a2), fmaxf(bv1, a1));
            if (a1 < bv1 || (a1 == bv1 && ak < bk)) { bv1 = a1; bk = ak; }
            bv2 = nv2;
        }
        int n = tok0 + tid;
        bestk[n] = bk;
        if (bv2 - bv1 < MARGIN) rlist[atomicAdd(rcount, 1)] = n;
    }
}

// ================= exact fp32 refine, 8 tokens per block-iteration ==========
__global__ __launch_bounds__(256)
void vq_refine(const float* __restrict__ x, const float* __restrict__ cb,
               const float* __restrict__ csq, const int* __restrict__ rcount,
               const int* __restrict__ rlist, int* __restrict__ bestk) {
    __shared__ float xv[8][256];
    __shared__ float xsq[8];
    __shared__ float wredv[4][8];
    __shared__ int   wredk[4][8];
    const int tid = threadIdx.x;
    const int cnt = min(rcount[0], N_);
    for (int base = blockIdx.x * 8; base < cnt; base += gridDim.x * 8) {
        const int m = min(8, cnt - base);
        __syncthreads();
        #pragma unroll
        for (int j = 0; j < 8; ++j) {
            if (j < m) {
                int n = rlist[base + j];
                int b = n >> 10, hw = n & 1023;
                xv[j][tid] = x[(size_t)b * DHW + (size_t)tid * HW_ + hw];
            }
        }
        __syncthreads();
        if (tid < 8) {
            float s = 0.f;
            for (int d = 0; d < 256; ++d) { float v = xv[tid][d]; s = fmaf(v, v, s); }
            xsq[tid] = s;
        }
        __syncthreads();
        float bv[8]; int bk[8];
        #pragma unroll
        for (int j = 0; j < 8; ++j) { bv[j] = 3.4e38f; bk[j] = 0; }
        for (int c4 = 0; c4 < 4; ++c4) {
            const int code = c4 * 256 + tid;
            const float* cp = cb + (size_t)code * D_;
            float dot[8];
            #pragma unroll
            for (int j = 0; j < 8; ++j) dot[j] = 0.f;
            for (int d = 0; d < 256; ++d) {
                float cv = cp[d];
                #pragma unroll
                for (int j = 0; j < 8; ++j) dot[j] = fmaf(cv, xv[j][d], dot[j]);
            }
            float cs = csq[code];
            #pragma unroll
            for (int j = 0; j < 8; ++j) {
                float dist = fmaf(-2.f, dot[j], xsq[j]) + cs;
                if (dist < bv[j] || (dist == bv[j] && code < bk[j])) { bv[j] = dist; bk[j] = code; }
            }
        }
        #pragma unroll
        for (int j = 0; j < 8; ++j) {
            if (j < m) {
                float v = bv[j]; int k = bk[j];
                #pragma unroll
                for (int mm = 1; mm < 64; mm <<= 1) {
                    float ov = __shfl_xor(v, mm, 64);
                    int   ok = __shfl_xor(k, mm, 64);
                    if (ov < v || (ov == v && ok < k)) { v = ov; k = ok; }
                }
                if ((tid & 63) == 0) { wredv[tid >> 6][j] = v; wredk[tid >> 6][j] = k; }
            }
        }
        __syncthreads();
        if (tid < m) {
            float v = wredv[0][tid]; int k = wredk[0][tid];
            #pragma unroll
            for (int q = 1; q < 4; ++q) {
                if (wredv[q][tid] < v || (wredv[q][tid] == v && wredk[q][tid] < k)) {
                    v = wredv[q][tid]; k = wredk[q][tid];
                }
            }
            bestk[rlist[base + tid]] = k;
        }
        __syncthreads();
    }
}

// ================= gather codewords, write out/idx, losses ==========
__global__ __launch_bounds__(256)
void vq_gather(const float* __restrict__ x, const float* __restrict__ cb,
               const int* __restrict__ bestk, float* __restrict__ out,
               float* __restrict__ oidx, float* __restrict__ oloss) {
    const int n0 = blockIdx.x * 64;
    const int tid = threadIdx.x;
    const int j = tid & 63, dg = tid >> 6;
    const int n = n0 + j;
    const int b = n >> 10, hw = n & 1023;
    const int k = bestk[n];
    const float* cw = cb + (size_t)k * D_;
    const size_t basex = (size_t)b * DHW + hw;
    float lsum = 0.f;
    #pragma unroll 4
    for (int d = dg * 64; d < dg * 64 + 64; ++d) {
        float q  = cw[d];
        float xvv = x[basex + (size_t)d * HW_];
        out[basex + (size_t)d * HW_] = q;
        float df = xvv - q;
        lsum = fmaf(df, df, lsum);
    }
    #pragma unroll
    for (int off = 32; off >= 1; off >>= 1) lsum += __shfl_xor(lsum, off, 64);
    if ((tid & 63) == 0) {
        float v = lsum * (1.0f / 8388608.0f);
        atomicAdd(&oloss[0], v);
        atomicAdd(&oloss[1], v);
    }
    if (tid < 64) oidx[n0 + tid] = (float)bestk[n0 + tid];
}

extern "C" void kernel_launch(void* const* d_in, const int* in_sizes, int n_in,
                              void* d_out, int out_size, void* d_ws, size_t ws_size,
                              hipStream_t stream) {
    const float* x  = (const float*)d_in[0];
    const float* cb = (const float*)d_in[1];

    float* out   = (float*)d_out;            // 8388608 floats
    float* oidx  = out + 8388608;            // 32768 floats
    float* oloss = out + 8388608 + 32768;    // 2 floats

    // d_out's first 16 MB reused as scratch for the bf16 token plane
    uint4* xg = (uint4*)d_out;               // [32768][32] uint4

    uint* wsb = (uint*)d_ws;
    uint4*  cbt   = (uint4*)wsb;             // 65536 uint4 (1 MB)
    float*  csq   = (float*)(wsb + 262144);  // 1024
    int*    bestk = (int*)  (wsb + 263168);  // 32768
    int*    rcount= (int*)  (wsb + 295936);  // 1
    int*    rlist = (int*)  (wsb + 295940);  // 32768

    hipMemsetAsync(oloss, 0, 2 * sizeof(float), stream);
    hipMemsetAsync(rcount, 0, sizeof(int), stream);

    prep_x  <<<512, 256, 0, stream>>>(x, xg);
    prep_cb <<<1024, 256, 0, stream>>>(cb, cbt, csq);
    vq_main <<<256, 512, 0, stream>>>(xg, cbt, csq, bestk, rcount, rlist);
    vq_refine<<<64, 256, 0, stream>>>(x, cb, csq, rcount, rlist, bestk);
    vq_gather<<<512, 256, 0, stream>>>(x, cb, bestk, out, oidx, oloss);
}